// Round 3
// baseline (1251.854 us; speedup 1.0000x reference)
//
#include <hip/hip_runtime.h>
#include <hip/hip_bf16.h>

// Problem constants
#define DIM   4096
#define SEQ   2048
#define NH    32
#define HD    128
#define BSZ   2
#define SEG   16777216   // 4096*4096 elements (x, each weight, each activation)

typedef unsigned short u16;
typedef unsigned int   u32;
typedef __attribute__((ext_vector_type(8))) short bf16x8;
typedef __attribute__((ext_vector_type(4))) float f32x4;
typedef __attribute__((ext_vector_type(16))) float f32x16;
typedef __attribute__((ext_vector_type(4))) u16   u16x4;

__device__ __forceinline__ float b2f(u16 u) {
    union { u32 i; float f; } c; c.i = ((u32)u) << 16; return c.f;
}
__device__ __forceinline__ u16 f2b(float f) {
    u32 x = __float_as_uint(f);
    return (u16)((x + 0x7FFFu + ((x >> 16) & 1u)) >> 16);  // RNE
}
__device__ __forceinline__ void gload_lds16(const void* g, void* l) {
    __builtin_amdgcn_global_load_lds(
        (__attribute__((address_space(1))) void*)(unsigned long)(g),
        (__attribute__((address_space(3))) void*)(l), 16, 0, 0);
}

#define BARRIER() do { asm volatile("" ::: "memory"); \
                       __builtin_amdgcn_s_barrier(); \
                       asm volatile("" ::: "memory"); } while (0)

// ---------------------------------------------------------------------------
// 1) cast x + wq + wk + wv + wo (fp32) -> bf16, contiguous into ws segments 0..4
// ---------------------------------------------------------------------------
__global__ __launch_bounds__(256) void cast5(const float* __restrict__ x,
                                             const float* __restrict__ wq,
                                             const float* __restrict__ wk,
                                             const float* __restrict__ wv,
                                             const float* __restrict__ wo,
                                             u16* __restrict__ dst) {
    int i = blockIdx.x * 1024 + threadIdx.x * 4;   // 4 elems per thread
    int seg = i >> 24;                              // SEG == 2^24
    int off = i & (SEG - 1);
    const float* s = x;
    if (seg == 1) s = wq; else if (seg == 2) s = wk;
    else if (seg == 3) s = wv; else if (seg == 4) s = wo;
    float4 v = *(const float4*)(s + off);
    u16x4 o; o.x = f2b(v.x); o.y = f2b(v.y); o.z = f2b(v.z); o.w = f2b(v.w);
    *(u16x4*)(dst + i) = o;
}

// ---------------------------------------------------------------------------
// 2) GEMM  C[M,N] = A[M,K] * B[N,K]^T   (bf16 in, bf16 or fp32 out)
//    256x256 tile, BK=64, 8 waves (2M x 4N), 8-phase counted-vmcnt schedule.
//    MFMA shape: 32x32x16 (µbench 2495 TF vs 2176 for 16x16x32; half the
//    instruction count for the same FLOP). LDS = 8 x 16KiB half-tile chunks
//    [dbuf][Ah0,Ah1,Bh0,Bh1]. Staging: linear gload_lds dest + inverse-
//    swizzled global source; ds_read applies the same swizzle:
//    swz(byte) = byte ^ (((byte>>7)&3)<<4)  (involution).
//    A/B frag: row/col = lane&31, k = ks*16 + (lane>>5)*8 + i  (bf16x8)
//    C/D frag: col = lane&31, row = (reg&3) + 8*(reg>>2) + 4*(lane>>5)
//    grid: (N/256, M/256, nz); B/C advanced by z*SEG.
// ---------------------------------------------------------------------------
template<int OUT_BF16>
__global__ __launch_bounds__(512, 2) void gemm8p(const u16* __restrict__ A,
                                                 const u16* __restrict__ Bbase,
                                                 void* __restrict__ Cv) {
    __shared__ __align__(16) char lds[131072];   // 128 KiB

    const int tid = threadIdx.x;
    const int lane = tid & 63, w = tid >> 6;     // 8 waves
    const int l31 = lane & 31;
    const int r16 = lane & 15;                    // row within 16-row group
    const int g32 = (lane >> 4) & 1;              // 16-group within 32-row window
    const int kh8 = lane >> 5;                    // k-offset-8 selector
    const int wm = w >> 2, wn = w & 3;           // wave tile: 128 rows x 64 cols
    const int m0 = blockIdx.y * 256, n0 = blockIdx.x * 256;
    const u16* Bp = Bbase + (size_t)blockIdx.z * SEG;

    // --- staging source decode: LDS linear byte p  <-  element at swz(p) ---
    const u16* aSrc[2];
    const u16* bSrc[2];
#pragma unroll
    for (int i = 0; i < 2; ++i) {
        int p = i * 8192 + w * 1024 + lane * 16;           // byte in 16KiB chunk
        int q = p ^ (((p >> 7) & 3) << 4);                  // inverse swizzle
        int rowoff = (q >> 11) * 16 + ((q >> 6) & 15);      // r16g*16 + r
        int coloff = (((q >> 10) & 1) << 5) + ((q & 63) >> 1); // c32g*32 + c
        aSrc[i] = A  + (size_t)(m0 + rowoff) * DIM + coloff;
        bSrc[i] = Bp + (size_t)(n0 + rowoff) * DIM + coloff;
    }
    // per-lane swizzled ds_read components (within a chunk)
    const int rgoff = g32 * 2048 + r16 * 64;               // row base bytes
    const int xsw   = (r16 >> 1) & 3;                      // swizzle source bits
    const int gA    = ((kh8)     ^ xsw) * 16;              // granule for even ks
    const int gB    = ((2 | kh8) ^ xsw) * 16;              // granule for odd ks

    f32x16 acc[4][2];
#pragma unroll
    for (int a = 0; a < 4; ++a)
#pragma unroll
        for (int b = 0; b < 2; ++b) acc[a][b] = 0.f;

    bf16x8 af[2][4];   // current 64-row half: 2 x 32-row windows x 4 k-steps
    bf16x8 bfr[2][4];  // both 32-col windows x 4 k-steps

// chunk ids: (d*4 + 0/1) = A half0/1 ; (d*4 + 2 + 0/1) = B half0/1
#define STAGE_A(d, h, kt) do { int kk_ = ((kt) & 63) * 64;                       \
    gload_lds16(aSrc[0] + (size_t)(h) * (128 * DIM) + kk_,                       \
                lds + ((d) * 4 + (h)) * 16384 + w * 1024);                       \
    gload_lds16(aSrc[1] + (size_t)(h) * (128 * DIM) + kk_,                       \
                lds + ((d) * 4 + (h)) * 16384 + 8192 + w * 1024); } while (0)
#define STAGE_B(d, h, kt) do { int kk_ = ((kt) & 63) * 64;                       \
    gload_lds16(bSrc[0] + (size_t)(h) * (128 * DIM) + kk_,                       \
                lds + ((d) * 4 + 2 + (h)) * 16384 + w * 1024);                   \
    gload_lds16(bSrc[1] + (size_t)(h) * (128 * DIM) + kk_,                       \
                lds + ((d) * 4 + 2 + (h)) * 16384 + 8192 + w * 1024); } while (0)
#define LOAD_A(d, mh) do {                                                       \
    const char* base_ = lds + ((d) * 4 + wm) * 16384 + (mh) * 8192 + rgoff;      \
    _Pragma("unroll") for (int m2 = 0; m2 < 2; ++m2) {                           \
        af[m2][0] = *(const bf16x8*)(base_ + m2 * 4096 + gA);                    \
        af[m2][1] = *(const bf16x8*)(base_ + m2 * 4096 + gB);                    \
        af[m2][2] = *(const bf16x8*)(base_ + m2 * 4096 + 1024 + gA);             \
        af[m2][3] = *(const bf16x8*)(base_ + m2 * 4096 + 1024 + gB); } } while (0)
#define LOAD_B(d, nh) do {                                                       \
    const char* base_ = lds + ((d) * 4 + 2 + (wn >> 1)) * 16384                  \
                        + (wn & 1) * 8192 + (nh) * 4096 + rgoff;                 \
        bfr[nh][0] = *(const bf16x8*)(base_ + gA);                               \
        bfr[nh][1] = *(const bf16x8*)(base_ + gB);                               \
        bfr[nh][2] = *(const bf16x8*)(base_ + 1024 + gA);                        \
        bfr[nh][3] = *(const bf16x8*)(base_ + 1024 + gB); } while (0)
#define MFMA_Q(mh, nh) do {                                                      \
    _Pragma("unroll") for (int m2 = 0; m2 < 2; ++m2)                             \
    _Pragma("unroll") for (int ks = 0; ks < 4; ++ks)                             \
        acc[(mh) * 2 + m2][nh] = __builtin_amdgcn_mfma_f32_32x32x16_bf16(        \
            af[m2][ks], bfr[nh][ks], acc[(mh) * 2 + m2][nh], 0, 0, 0); } while (0)

    // prologue: tile0 fully + tile1 B halves; force tile0 landed (residue = t1.B)
    STAGE_B(0, 0, 0); STAGE_B(0, 1, 0); STAGE_A(0, 0, 0); STAGE_A(0, 1, 0);
    STAGE_B(1, 0, 1); STAGE_B(1, 1, 1);
    asm volatile("s_waitcnt vmcnt(4)" ::: "memory");
    BARRIER();

    for (int it = 0; it < 32; ++it) {           // 2 K-tiles / iter, 64 tiles
        const int t = 2 * it;
        // ---- P1: reads tile t (a-lo, b-lo); stage (t+1).Ah0 -> buf1
        LOAD_A(0, 0); LOAD_B(0, 0);
        STAGE_A(1, 0, t + 1);
        asm volatile("s_waitcnt lgkmcnt(8)" ::: "memory");
        BARRIER();
        asm volatile("s_waitcnt lgkmcnt(0)" ::: "memory");
        __builtin_amdgcn_s_setprio(1); MFMA_Q(0, 0); __builtin_amdgcn_s_setprio(0);
        BARRIER();
        // ---- P2: b-hi; stage (t+1).Ah1 -> buf1
        LOAD_B(0, 1);
        STAGE_A(1, 1, t + 1);
        BARRIER();
        asm volatile("s_waitcnt lgkmcnt(0)" ::: "memory");
        __builtin_amdgcn_s_setprio(1); MFMA_Q(0, 1); __builtin_amdgcn_s_setprio(0);
        BARRIER();
        // ---- P3: a-hi; stage (t+2).Bh0 -> buf0 (buf0.B reads done after P2)
        LOAD_A(0, 1);
        STAGE_B(0, 0, t + 2);
        BARRIER();
        asm volatile("s_waitcnt lgkmcnt(0)" ::: "memory");
        __builtin_amdgcn_s_setprio(1); MFMA_Q(1, 1); __builtin_amdgcn_s_setprio(0);
        BARRIER();
        // ---- P4: stage (t+2).Bh1; vmcnt(4) forces tile t+1 fully landed
        STAGE_B(0, 1, t + 2);
        BARRIER();
        __builtin_amdgcn_s_setprio(1); MFMA_Q(1, 0); __builtin_amdgcn_s_setprio(0);
        asm volatile("s_waitcnt vmcnt(4)" ::: "memory");
        BARRIER();
        // ---- P5: reads tile t+1; stage (t+2).Ah0 -> buf0 (buf0.A free after P3)
        LOAD_A(1, 0); LOAD_B(1, 0);
        STAGE_A(0, 0, t + 2);
        asm volatile("s_waitcnt lgkmcnt(8)" ::: "memory");
        BARRIER();
        asm volatile("s_waitcnt lgkmcnt(0)" ::: "memory");
        __builtin_amdgcn_s_setprio(1); MFMA_Q(0, 0); __builtin_amdgcn_s_setprio(0);
        BARRIER();
        // ---- P6: stage (t+2).Ah1
        LOAD_B(1, 1);
        STAGE_A(0, 1, t + 2);
        BARRIER();
        asm volatile("s_waitcnt lgkmcnt(0)" ::: "memory");
        __builtin_amdgcn_s_setprio(1); MFMA_Q(0, 1); __builtin_amdgcn_s_setprio(0);
        BARRIER();
        // ---- P7: stage (t+3).Bh0 -> buf1 (buf1.B reads done after P6)
        LOAD_A(1, 1);
        STAGE_B(1, 0, t + 3);
        BARRIER();
        asm volatile("s_waitcnt lgkmcnt(0)" ::: "memory");
        __builtin_amdgcn_s_setprio(1); MFMA_Q(1, 1); __builtin_amdgcn_s_setprio(0);
        BARRIER();
        // ---- P8: stage (t+3).Bh1; vmcnt(4) forces tile t+2 fully landed
        STAGE_B(1, 1, t + 3);
        BARRIER();
        __builtin_amdgcn_s_setprio(1); MFMA_Q(1, 0); __builtin_amdgcn_s_setprio(0);
        asm volatile("s_waitcnt vmcnt(4)" ::: "memory");
        BARRIER();
    }
    asm volatile("s_waitcnt vmcnt(0)" ::: "memory");  // drain tail garbage stages

#pragma unroll
    for (int mt = 0; mt < 4; ++mt)
#pragma unroll
        for (int nt = 0; nt < 2; ++nt) {
            const int col = n0 + wn * 64 + nt * 32 + l31;
#pragma unroll
            for (int q4 = 0; q4 < 4; ++q4) {
                const int row = m0 + wm * 128 + mt * 32 + q4 * 8 + kh8 * 4;
                if (OUT_BF16) {
                    u16* C = (u16*)Cv + (size_t)blockIdx.z * SEG;
#pragma unroll
                    for (int r = 0; r < 4; ++r)
                        C[(size_t)(row + r) * DIM + col] = f2b(acc[mt][nt][q4 * 4 + r]);
                } else {
                    float* C = (float*)Cv + (size_t)blockIdx.z * SEG;
#pragma unroll
                    for (int r = 0; r < 4; ++r)
                        C[(size_t)(row + r) * DIM + col] = acc[mt][nt][q4 * 4 + r];
                }
            }
        }
#undef STAGE_A
#undef STAGE_B
#undef LOAD_A
#undef LOAD_B
#undef MFMA_Q
}

// ---------------------------------------------------------------------------
// 3) RoPE on xq, xk. Writes q_b, k_b (bf16) and new_hidden[0] (fp32).
// ---------------------------------------------------------------------------
__global__ __launch_bounds__(256) void rope(const u16* __restrict__ XQ,
                                            const u16* __restrict__ XK,
                                            const float* __restrict__ FC,
                                            u16* __restrict__ Qo,
                                            u16* __restrict__ Ko,
                                            float* __restrict__ KH) {
    int tid = blockIdx.x * 256 + threadIdx.x;   // ((b*S+s)*NH+h)*64 + i
    int i = tid & 63;
    int s = (tid >> 11) & 2047;
    float2 cs = *(const float2*)(FC + (s * 64 + i) * 2);
    u32 q = ((const u32*)XQ)[tid];
    u32 k = ((const u32*)XK)[tid];
    float q0 = b2f((u16)(q & 0xffff)), q1 = b2f((u16)(q >> 16));
    float k0 = b2f((u16)(k & 0xffff)), k1 = b2f((u16)(k >> 16));
    float qr = q0 * cs.x - q1 * cs.y, qi = q0 * cs.y + q1 * cs.x;
    float kr = k0 * cs.x - k1 * cs.y, ki = k0 * cs.y + k1 * cs.x;
    ((u32*)Qo)[tid] = (u32)f2b(qr) | ((u32)f2b(qi) << 16);
    ((u32*)Ko)[tid] = (u32)f2b(kr) | ((u32)f2b(ki) << 16);
    *(float2*)(KH + (size_t)tid * 2) = make_float2(kr, ki);
}

// ---------------------------------------------------------------------------
// 4) V prep: new_hidden[1] (fp32) + transposed Vt (bf16, [bh][d][s])
// ---------------------------------------------------------------------------
__global__ __launch_bounds__(256) void vprep(const u16* __restrict__ XV,
                                             float* __restrict__ VH,
                                             u16* __restrict__ VT) {
    __shared__ u16 tile[64][65];
    int bs = blockIdx.x;        // s-tile (32)
    int bd = blockIdx.y;        // d-tile (2)
    int bh = blockIdx.z;        // (64)
    int b = bh >> 5, h = bh & 31;
    int t = threadIdx.x;
    int c = t & 63, r4 = t >> 6;
    for (int i = 0; i < 16; ++i) {
        int sr = i * 4 + r4;
        int gi = ((b * SEQ + bs * 64 + sr) * NH + h) * HD + bd * 64 + c;
        u16 v = XV[gi];
        VH[gi] = b2f(v);
        tile[sr][c] = v;
    }
    __syncthreads();
    for (int i = 0; i < 16; ++i) {
        int dr = i * 4 + r4;
        VT[(bh * HD + bd * 64 + dr) * SEQ + bs * 64 + c] = tile[c][dr];
    }
}

// ---------------------------------------------------------------------------
// 5) Causal flash attention v2.
//    Block = 128 q-rows, 4 waves x 32 rows (2 m-frags). KV tile = 64.
//    T14 async-STAGE: K/V reg-staged (global->reg issued one tile ahead,
//    ds_write after barrier) so compute hides HBM latency; raw s_barrier +
//    per-wave lgkmcnt(0), NO vmcnt drain mid-loop.
//    k_lds[64 s][128 d]  chunk swizzle p = c ^ (s&15)
//    v_lds[128 d][64 s]  chunk swizzle p = c ^ (d&7)
// ---------------------------------------------------------------------------
__global__ __launch_bounds__(256, 2) void flash(const u16* __restrict__ Q,
                                                const u16* __restrict__ K,
                                                const u16* __restrict__ Vt,
                                                u16* __restrict__ O) {
    __shared__ __align__(16) u16 k_lds[64 * 128];
    __shared__ __align__(16) u16 v_lds[128 * 64];
    __shared__ __align__(16) u16 p_lds[4][32 * 68];

    const int tid = threadIdx.x, lane = tid & 63, w = tid >> 6;
    const int quad = lane >> 4, m16 = lane & 15;
    const int bh = blockIdx.x;                 // 0..63
    const int b = bh >> 5, h = bh & 31;
    const int qt = (gridDim.y - 1) - blockIdx.y;   // long blocks dispatch first
    const int q0 = qt * 128;
    const int wrow = q0 + w * 32;              // this wave's 32 q-rows

    const u16* Kbase = K + ((size_t)(b * SEQ) * NH + h) * HD;
    const u16* Vbase = Vt + (size_t)(bh * HD) * SEQ;

    // per-thread staging sources (pre-inverse-swizzled) + linear LDS dests
    const u16* ksrc[4];
    const u16* vsrc[4];
#pragma unroll
    for (int j = 0; j < 4; ++j) {
        int g = w * 256 + lane + j * 64;
        int rK = g >> 4, cK = (g & 15) ^ (rK & 15);
        ksrc[j] = Kbase + (size_t)rK * DIM + cK * 8;
        int rV = g >> 3, cV = (g & 7) ^ (rV & 7);
        vsrc[j] = Vbase + (size_t)rV * SEQ + cV * 8;
    }

    bf16x8 qa[2][4];
#pragma unroll
    for (int mt = 0; mt < 2; ++mt) {
        const u16* qp = Q + ((size_t)(b * SEQ + wrow + mt * 16 + m16) * NH + h) * HD;
#pragma unroll
        for (int ks = 0; ks < 4; ++ks) qa[mt][ks] = *(const bf16x8*)(qp + ks * 32 + quad * 8);
    }

    float mi[2][4], li[2][4];
    f32x4 o[2][8];
#pragma unroll
    for (int mt = 0; mt < 2; ++mt)
#pragma unroll
        for (int r = 0; r < 4; ++r) { mi[mt][r] = -1e30f; li[mt][r] = 0.f; }
#pragma unroll
    for (int mt = 0; mt < 2; ++mt)
#pragma unroll
        for (int n = 0; n < 8; ++n) o[mt][n] = 0.f;

    const float scale = 0.08838834764831845f;   // 1/sqrt(128)
    const int nkt = 2 * qt + 2;

    // prologue: issue tile-0 loads into registers
    uint4 kreg[4], vreg[4];
#pragma unroll
    for (int j = 0; j < 4; ++j) {
        kreg[j] = *(const uint4*)(ksrc[j]);
        vreg[j] = *(const uint4*)(vsrc[j]);
    }

    for (int kt = 0; kt < nkt; ++kt) {
        const int k0 = kt * 64;
        // tile kt regs landed; all waves done reading previous tile
        asm volatile("s_waitcnt vmcnt(0)" ::: "memory");
        asm volatile("s_waitcnt lgkmcnt(0)" ::: "memory");
        BARRIER();
        // write tile kt to LDS (linear dest = same layout gload_lds produced)
#pragma unroll
        for (int j = 0; j < 4; ++j) {
            *(uint4*)((char*)k_lds + w * 4096 + j * 1024 + lane * 16) = kreg[j];
            *(uint4*)((char*)v_lds + w * 4096 + j * 1024 + lane * 16) = vreg[j];
        }
        // issue tile kt+1 loads (hidden under this tile's compute)
        if (kt + 1 < nkt) {
            const int kn = (kt + 1) * 64;
#pragma unroll
            for (int j = 0; j < 4; ++j) {
                kreg[j] = *(const uint4*)(ksrc[j] + (size_t)kn * DIM);
                vreg[j] = *(const uint4*)(vsrc[j] + kn);
            }
        }
        asm volatile("s_waitcnt lgkmcnt(0)" ::: "memory");  // my ds_writes done
        BARRIER();

        if (k0 <= wrow + 31) {
            // ---- QK^T : S (2 x 16 q-rows) x 64 k-cols
            f32x4 s[2][4];
#pragma unroll
            for (int mt = 0; mt < 2; ++mt)
#pragma unroll
                for (int nt = 0; nt < 4; ++nt) s[mt][nt] = 0.f;
#pragma unroll
            for (int ks = 0; ks < 4; ++ks)
#pragma unroll
                for (int nt = 0; nt < 4; ++nt) {
                    int rk = nt * 16 + m16;
                    int p = (ks * 4 + quad) ^ m16;
                    bf16x8 kb = *(const bf16x8*)(k_lds + rk * 128 + p * 8);
#pragma unroll
                    for (int mt = 0; mt < 2; ++mt)
                        s[mt][nt] = __builtin_amdgcn_mfma_f32_16x16x32_bf16(
                            qa[mt][ks], kb, s[mt][nt], 0, 0, 0);
                }

            // ---- online softmax per m-frag
#pragma unroll
            for (int mt = 0; mt < 2; ++mt) {
                float sv[4][4];
                const bool need_mask = (k0 + 63) > (wrow + mt * 16);
#pragma unroll
                for (int nt = 0; nt < 4; ++nt)
#pragma unroll
                    for (int r = 0; r < 4; ++r) {
                        float v = s[mt][nt][r] * scale;
                        if (need_mask) {
                            int col = k0 + nt * 16 + m16;
                            int rq = wrow + mt * 16 + quad * 4 + r;
                            if (col > rq) v = -1e30f;
                        }
                        sv[nt][r] = v;
                    }
#pragma unroll
                for (int r = 0; r < 4; ++r) {
                    float mx = fmaxf(fmaxf(sv[0][r], sv[1][r]), fmaxf(sv[2][r], sv[3][r]));
#pragma unroll
                    for (int off = 8; off >= 1; off >>= 1) mx = fmaxf(mx, __shfl_xor(mx, off));
                    float mnew = fmaxf(mi[mt][r], mx);
                    float alpha = __expf(mi[mt][r] - mnew);
                    float sum = 0.f;
#pragma unroll
                    for (int nt = 0; nt < 4; ++nt) {
                        float pv = __expf(sv[nt][r] - mnew);
                        sum += pv;
                        p_lds[w][(mt * 16 + quad * 4 + r) * 68 + nt * 16 + m16] = f2b(pv);
                    }
#pragma unroll
                    for (int off = 8; off >= 1; off >>= 1) sum += __shfl_xor(sum, off);
                    li[mt][r] = li[mt][r] * alpha + sum;
                    mi[mt][r] = mnew;
#pragma unroll
                    for (int n8 = 0; n8 < 8; ++n8) o[mt][n8][r] *= alpha;
                }
            }

            // own-wave LDS ordering: P writes -> P reads
            asm volatile("s_waitcnt lgkmcnt(0)" ::: "memory");

            // ---- PV : O += P (2x16 x 64) * V-tile (64 x 128)
#pragma unroll
            for (int ks2 = 0; ks2 < 2; ++ks2) {
                bf16x8 pa[2];
#pragma unroll
                for (int mt = 0; mt < 2; ++mt)
                    pa[mt] = *(const bf16x8*)(&p_lds[w][0] + (mt * 16 + m16) * 68 + ks2 * 32 + quad * 8);
#pragma unroll
                for (int n8 = 0; n8 < 8; ++n8) {
                    int rv = n8 * 16 + m16;
                    int p = (ks2 * 4 + quad) ^ (m16 & 7);
                    bf16x8 vb = *(const bf16x8*)(v_lds + rv * 64 + p * 8);
#pragma unroll
                    for (int mt = 0; mt < 2; ++mt)
                        o[mt][n8] = __builtin_amdgcn_mfma_f32_16x16x32_bf16(
                            pa[mt], vb, o[mt][n8], 0, 0, 0);
                }
            }
        }
    }

#pragma unroll
    for (int mt = 0; mt < 2; ++mt) {
        float inv[4];
#pragma unroll
        for (int r = 0; r < 4; ++r) inv[r] = 1.0f / li[mt][r];
#pragma unroll
        for (int n8 = 0; n8 < 8; ++n8)
#pragma unroll
            for (int r = 0; r < 4; ++r) {
                int rq = wrow + mt * 16 + quad * 4 + r;
                O[((size_t)(b * SEQ + rq) * NH + h) * HD + n8 * 16 + m16] =
                    f2b(o[mt][n8][r] * inv[r]);
            }
    }
}

// ---------------------------------------------------------------------------
// launch — ws layout (bf16 elems, SEG each):
//  0: x_b (→ q_rope)  1: wq_b (→ k_rope)  2: wk_b (→ Vt)  3: wv_b (→ attn_out)
//  4: wo_b  5: xq_b  6: xk_b  7: xv_b
// ---------------------------------------------------------------------------
extern "C" void kernel_launch(void* const* d_in, const int* in_sizes, int n_in,
                              void* d_out, int out_size, void* d_ws, size_t ws_size,
                              hipStream_t stream) {
    const float* x  = (const float*)d_in[0];
    const float* fc = (const float*)d_in[1];
    const float* wq = (const float*)d_in[4];
    const float* wk = (const float*)d_in[5];
    const float* wv = (const float*)d_in[6];
    const float* wo = (const float*)d_in[7];

    float* out = (float*)d_out;
    float* kh  = out + 16777216;             // new_hidden[0]
    float* vh  = out + 33554432;             // new_hidden[1]

    u16* ws = (u16*)d_ws;
    u16* xb  = ws + 0L * SEG;
    u16* wqb = ws + 1L * SEG;
    u16* wkb = ws + 2L * SEG;
    u16* wvb = ws + 3L * SEG;
    u16* wob = ws + 4L * SEG;
    u16* xqb = ws + 5L * SEG;
    u16* xkb = ws + 6L * SEG;
    u16* xvb = ws + 7L * SEG;
    u16* qro = xb;    // q after rope
    u16* kro = wqb;   // k after rope
    u16* vt  = wkb;   // transposed V
    u16* ao  = wvb;   // attention output

    cast5<<<dim3(81920), dim3(256), 0, stream>>>(x, wq, wk, wv, wo, ws);
    gemm8p<1><<<dim3(16, 16, 3), dim3(512), 0, stream>>>(xb, wqb, (void*)xqb);
    rope<<<dim3(32768), dim3(256), 0, stream>>>(xqb, xkb, fc, qro, kro, kh);
    vprep<<<dim3(32, 2, 64), dim3(256), 0, stream>>>(xvb, vh, vt);
    flash<<<dim3(64, 16), dim3(256), 0, stream>>>(qro, kro, vt, ao);
    gemm8p<0><<<dim3(16, 16, 1), dim3(512), 0, stream>>>(ao, wob, (void*)out);
}